// Round 2
// baseline (822.752 us; speedup 1.0000x reference)
//
#include <hip/hip_runtime.h>
#include <math.h>

#define Gn 64
#define Nn 1000
#define En 8192
#define Cc 128
#define HIDn 256
#define EPSf 1e-5f

typedef __attribute__((ext_vector_type(8))) short bh8;
typedef __attribute__((ext_vector_type(4))) float fx4;

__device__ __forceinline__ unsigned short f2bf(float f) {
    unsigned u = __float_as_uint(f);
    u += 0x7fffu + ((u >> 16) & 1u);
    return (unsigned short)(u >> 16);
}
__device__ __forceinline__ float bflo(unsigned u) { return __uint_as_float(u << 16); }
__device__ __forceinline__ float bfhi(unsigned u) { return __uint_as_float(u & 0xffff0000u); }

// ---------------- prep: degree count + scan + CSR(src,w) fill, per graph ----------------
__global__ __launch_bounds__(1024) void k_prep(const int* __restrict__ ei, int* __restrict__ offs,
                                               int* __restrict__ degg, float* __restrict__ selfw,
                                               int2* __restrict__ epair, float* __restrict__ pooled)
{
    __shared__ int degs[1024];
    __shared__ int sb[1024];
    __shared__ int cur[1024];
    __shared__ float dinv_s[1024];
    int g = blockIdx.x, t = threadIdx.x;
    const int* srcp = ei + (size_t)g * 2 * En;
    const int* dstp = srcp + En;
    degs[t] = 0;
    __syncthreads();
    for (int e = t; e < En; e += 1024) atomicAdd(&degs[dstp[e]], 1);
    __syncthreads();
    int d = (t < Nn) ? degs[t] : 0;
    sb[t] = d;
    __syncthreads();
    for (int st = 1; st < 1024; st <<= 1) {
        int v2 = (t >= st) ? sb[t - st] : 0;
        __syncthreads();
        sb[t] += v2;
        __syncthreads();
    }
    int ex = sb[t] - d;            // exclusive prefix
    float dv = rsqrtf((float)d + 1.0f);
    cur[t] = ex;
    dinv_s[t] = dv;
    if (t < Nn) {
        offs[g * Nn + t] = ex;
        degg[g * Nn + t] = d;
        selfw[g * Nn + t] = dv * dv;
    }
    __syncthreads();
    for (int e = t; e < En; e += 1024) {
        int dd = dstp[e], ss = srcp[e];
        int p = atomicAdd(&cur[dd], 1);
        float w = dinv_s[ss] * dinv_s[dd];
        epair[(size_t)g * En + p] = make_int2(ss, __float_as_int(w));
    }
    if (t < Cc) pooled[g * Cc + t] = 0.f;  // combine<POOL> accumulates later (same stream)
}

// ---------------- MFMA GEMM: H[g] = X[g] @ W, bf16 out. INBF: input is bf16 (else fp32) ----
template<int INBF>
__global__ __launch_bounds__(256) void k_gemm(const void* __restrict__ Xin, const float* __restrict__ W,
                                              unsigned short* __restrict__ Hout)
{
    __shared__ __align__(16) short Wt[128][136];   // W^T, 272B rows: 16B-aligned, uniform bank spread
    int b = blockIdx.x;
    int xcd = b & 7, j = b >> 3;
    int g = xcd + 8 * (j & 7);     // graph g on XCD g%8
    int rblk = j >> 3;             // 0..3, 256 rows each
    int t = threadIdx.x;
    for (int idx = t; idx < 16384; idx += 256) {
        int kI = idx >> 7, n = idx & 127;
        Wt[n][kI] = (short)f2bf(W[idx]);
    }
    __syncthreads();
    int wave = t >> 6, l = t & 63;
    int lr = l & 15, lg = l >> 4;
    const float* Xf = (const float*)Xin + (size_t)g * Nn * Cc;
    const short* Xh = (const short*)Xin + (size_t)g * Nn * Cc;
    unsigned short* Hg = Hout + (size_t)g * Nn * Cc;

    for (int s = 0; s < 4; ++s) {
        int rbase = rblk * 256 + wave * 64 + s * 16;
        int r = rbase + lr;
        bool ok = r < Nn;
        bh8 af[4];
        if (INBF) {
            #pragma unroll
            for (int ks = 0; ks < 4; ++ks) {
                if (ok) af[ks] = *(const bh8*)(Xh + (size_t)r * Cc + ks * 32 + lg * 8);
                else    af[ks] = bh8{0, 0, 0, 0, 0, 0, 0, 0};
            }
        } else {
            #pragma unroll
            for (int ks = 0; ks < 4; ++ks) {
                if (ok) {
                    const float* xp = Xf + (size_t)r * Cc + ks * 32 + lg * 8;
                    fx4 a0 = *(const fx4*)xp;
                    fx4 a1 = *(const fx4*)(xp + 4);
                    bh8 av;
                    av[0] = (short)f2bf(a0[0]); av[1] = (short)f2bf(a0[1]);
                    av[2] = (short)f2bf(a0[2]); av[3] = (short)f2bf(a0[3]);
                    av[4] = (short)f2bf(a1[0]); av[5] = (short)f2bf(a1[1]);
                    av[6] = (short)f2bf(a1[2]); av[7] = (short)f2bf(a1[3]);
                    af[ks] = av;
                } else af[ks] = bh8{0, 0, 0, 0, 0, 0, 0, 0};
            }
        }
        fx4 acc[8];
        #pragma unroll
        for (int ct = 0; ct < 8; ++ct) acc[ct] = fx4{0.f, 0.f, 0.f, 0.f};
        #pragma unroll
        for (int ks = 0; ks < 4; ++ks) {
            #pragma unroll
            for (int ct = 0; ct < 8; ++ct) {
                bh8 bfr = *(const bh8*)(&Wt[ct * 16 + lr][ks * 32 + lg * 8]);
                acc[ct] = __builtin_amdgcn_mfma_f32_16x16x32_bf16(af[ks], bfr, acc[ct], 0, 0, 0);
            }
        }
        // C/D layout: col = lane&15, row = (lane>>4)*4 + reg
        #pragma unroll
        for (int ct = 0; ct < 8; ++ct) {
            #pragma unroll
            for (int rg = 0; rg < 4; ++rg) {
                int row = rbase + lg * 4 + rg;
                if (row < Nn) Hg[(size_t)row * Cc + ct * 16 + lr] = f2bf(acc[ct][rg]);
            }
        }
    }
}

// ---------------- combine: tanh(b + selfw*H[n] + sum_e w_e*H[src_e]); POOL: accumulate ------
template<int POOL>
__global__ __launch_bounds__(256) void k_combine(const unsigned* __restrict__ Hb, const int2* __restrict__ epair,
                                                 const int* __restrict__ offs, const int* __restrict__ degg,
                                                 const float* __restrict__ selfw, const float* __restrict__ bias,
                                                 unsigned* __restrict__ Tout, float* __restrict__ pooled)
{
    int b = blockIdx.x;
    int xcd = b & 7, j = b >> 3;
    int g = xcd + 8 * (j & 7);     // same XCD as this graph's GEMM blocks
    int blk = j >> 3;              // 0..31
    int wave = threadIdx.x >> 6, lane = threadIdx.x & 63;
    const unsigned* Hg = Hb + (size_t)g * Nn * 64;   // rows of 64 uint = 128 bf16
    const int2* epg = epair + (size_t)g * En;
    float2 bb = *(const float2*)(bias + lane * 2);
    float px = 0.f, py = 0.f;
    for (int n = blk * 4 + wave; n < Nn; n += 128) {
        float sw = selfw[g * Nn + n];
        int st = offs[g * Nn + n];
        int dc = degg[g * Nn + n];
        unsigned hv = Hg[n * 64 + lane];
        float ax = bflo(hv) * sw + bb.x;
        float ay = bfhi(hv) * sw + bb.y;
        float bx = 0.f, by = 0.f;
        int e = 0;
        for (; e + 2 <= dc; e += 2) {
            int2 p0 = epg[st + e];
            int2 p1 = epg[st + e + 1];
            unsigned r0 = Hg[p0.x * 64 + lane];
            unsigned r1 = Hg[p1.x * 64 + lane];
            float w0 = __int_as_float(p0.y), w1 = __int_as_float(p1.y);
            ax = fmaf(bflo(r0), w0, ax); ay = fmaf(bfhi(r0), w0, ay);
            bx = fmaf(bflo(r1), w1, bx); by = fmaf(bfhi(r1), w1, by);
        }
        if (e < dc) {
            int2 p0 = epg[st + e];
            unsigned r0 = Hg[p0.x * 64 + lane];
            float w0 = __int_as_float(p0.y);
            ax = fmaf(bflo(r0), w0, ax); ay = fmaf(bfhi(r0), w0, ay);
        }
        ax += bx; ay += by;
        float tx = tanhf(ax), ty = tanhf(ay);
        if (POOL) { px += tx; py += ty; }
        else Tout[(size_t)(g * Nn + n) * 64 + lane] = ((unsigned)f2bf(ty) << 16) | (unsigned)f2bf(tx);
    }
    if (POOL) {
        atomicAdd(&pooled[g * Cc + lane * 2], px);
        atomicAdd(&pooled[g * Cc + lane * 2 + 1], py);
    }
}

// ---------------- fused head: qkv -> attn -> out-proj -> MLP -> LN -> relu-sum -> logits ----
__global__ __launch_bounds__(1024) void k_head(const float* __restrict__ pooled, const float* __restrict__ in_w,
                                               const float* __restrict__ in_b, const float* __restrict__ out_w,
                                               const float* __restrict__ out_b, const float* __restrict__ mw1,
                                               const float* __restrict__ mb1, const float* __restrict__ mw2,
                                               const float* __restrict__ mb2, const float* __restrict__ ln2g,
                                               const float* __restrict__ ln2b, const float* __restrict__ lw,
                                               const float* __restrict__ lb, float* __restrict__ out)
{
    __shared__ float LB[37056];    // 144.75 KB (gfx950 allows 160KB/workgroup)
    float* q  = LB;                // [64][129] (pad vs LDS bank conflicts)
    float* kk = LB + 8256;         // [64][129]
    float* v  = LB + 16512;        // [64][129]
    float* S  = LB + 24768;        // [64][64]
    float* o  = LB + 28864;        // [64][128]
    int t = threadIdx.x;
    int lane = t & 63, w = t >> 6;

    // qkv = pooled @ in_w.T + in_b (pooled read straight from L2)
    for (int idx = t; idx < 24576; idx += 1024) {
        int i = idx / 384, jj = idx - i * 384;
        const float* wr = in_w + jj * Cc;
        const float* pr = pooled + i * Cc;
        float acc = in_b[jj];
        #pragma unroll 4
        for (int k2 = 0; k2 < Cc; ++k2) acc = fmaf(pr[k2], wr[k2], acc);
        if (jj < 128)      q[i * 129 + jj] = acc;
        else if (jj < 256) kk[i * 129 + (jj - 128)] = acc;
        else               v[i * 129 + (jj - 256)] = acc;
    }
    __syncthreads();

    for (int h = 0; h < 4; ++h) {
        int base = h * 32;
        for (int idx = t; idx < 4096; idx += 1024) {
            int i = idx >> 6, jj = idx & 63;
            float acc = 0.f;
            #pragma unroll
            for (int d2 = 0; d2 < 32; ++d2)
                acc = fmaf(q[i * 129 + base + d2], kk[jj * 129 + base + d2], acc);
            S[idx] = acc * 0.17677669529663687f;
        }
        __syncthreads();
        for (int r = w; r < 64; r += 16) {
            float val = S[r * 64 + lane];
            float m = val;
            #pragma unroll
            for (int off = 32; off > 0; off >>= 1) m = fmaxf(m, __shfl_xor(m, off));
            float e2 = expf(val - m);
            float ssum = e2;
            #pragma unroll
            for (int off = 32; off > 0; off >>= 1) ssum += __shfl_xor(ssum, off);
            S[r * 64 + lane] = e2 / ssum;
        }
        __syncthreads();
        for (int idx = t; idx < 2048; idx += 1024) {
            int i = idx >> 5, d2 = idx & 31;
            float acc = 0.f;
            #pragma unroll 4
            for (int k2 = 0; k2 < 64; ++k2)
                acc = fmaf(S[i * 64 + k2], v[k2 * 129 + base + d2], acc);
            o[i * 128 + base + d2] = acc;
        }
        __syncthreads();
    }

    // out-proj -> xatt (reuse q; q dead after attention)
    float* xatt = q;
    for (int idx = t; idx < 8192; idx += 1024) {
        int i = idx >> 7, c = idx & 127;
        const float* wr = out_w + c * Cc;
        const float* orow = o + i * 128;
        float acc = out_b[c];
        #pragma unroll 4
        for (int k2 = 0; k2 < Cc; ++k2) acc = fmaf(orow[k2], wr[k2], acc);
        xatt[i * 129 + c] = acc;
    }
    __syncthreads();

    float* m1 = kk;   // [64][256] spans kk+v (both dead)
    for (int idx = t; idx < 16384; idx += 1024) {
        int i = idx >> 8, jh = idx & 255;
        float acc = mb1[jh];
        #pragma unroll 4
        for (int k2 = 0; k2 < Cc; ++k2) acc = fmaf(xatt[i * 129 + k2], mw1[k2 * HIDn + jh], acc);
        m1[i * 256 + jh] = fmaxf(acc, 0.f);
    }
    __syncthreads();

    float* y = LB + 24768;   // [64][128] (S/o dead)
    for (int idx = t; idx < 8192; idx += 1024) {
        int i = idx >> 7, c = idx & 127;
        float acc = mb2[c];
        #pragma unroll 4
        for (int j2 = 0; j2 < HIDn; ++j2) acc = fmaf(m1[i * 256 + j2], mw2[j2 * Cc + c], acc);
        y[idx] = xatt[i * 129 + c] + acc;
    }
    __syncthreads();

    // layernorm + relu, store to R (reuse m1 region)
    float* R = LB + 8256;    // [64][128]
    for (int r = w; r < 64; r += 16) {
        float v0 = y[r * 128 + lane];
        float v1 = y[r * 128 + 64 + lane];
        float s2 = v0 + v1;
        #pragma unroll
        for (int off = 32; off > 0; off >>= 1) s2 += __shfl_xor(s2, off);
        float mu = s2 * (1.f / 128.f);
        float d0 = v0 - mu, d1 = v1 - mu;
        float vv = d0 * d0 + d1 * d1;
        #pragma unroll
        for (int off = 32; off > 0; off >>= 1) vv += __shfl_xor(vv, off);
        float rstd = rsqrtf(vv * (1.f / 128.f) + EPSf);
        float z0 = d0 * rstd * ln2g[lane] + ln2b[lane];
        float z1 = d1 * rstd * ln2g[64 + lane] + ln2b[64 + lane];
        R[r * 128 + lane] = fmaxf(z0, 0.f);
        R[r * 128 + 64 + lane] = fmaxf(z1, 0.f);
    }
    __syncthreads();

    // column sums + logits (reuse xatt region for partials)
    float* L0 = LB;
    float* L1 = LB + 128;
    if (t < 128) {
        float acc = 0.f;
        for (int r = 0; r < 64; ++r) acc += R[r * 128 + t];
        L0[t] = acc * lw[t * 2 + 0];
        L1[t] = acc * lw[t * 2 + 1];
    }
    __syncthreads();
    for (int s2 = 64; s2 > 0; s2 >>= 1) {
        if (t < s2) { L0[t] += L0[t + s2]; L1[t] += L1[t + s2]; }
        __syncthreads();
    }
    if (t == 0) { out[0] = L0[0] + lb[0]; out[1] = L1[0] + lb[1]; }
}

extern "C" void kernel_launch(void* const* d_in, const int* in_sizes, int n_in,
                              void* d_out, int out_size, void* d_ws, size_t ws_size,
                              hipStream_t stream)
{
    const float* x     = (const float*)d_in[0];
    const int*   ei    = (const int*)d_in[1];
    const float* W0    = (const float*)d_in[2];
    const float* b0    = (const float*)d_in[3];
    const float* W1    = (const float*)d_in[4];
    const float* b1    = (const float*)d_in[5];
    const float* in_w  = (const float*)d_in[6];
    const float* in_b  = (const float*)d_in[7];
    const float* out_w = (const float*)d_in[8];
    const float* out_b = (const float*)d_in[9];
    const float* ln2g  = (const float*)d_in[10];
    const float* ln2b  = (const float*)d_in[11];
    const float* mw1   = (const float*)d_in[12];
    const float* mb1   = (const float*)d_in[13];
    const float* mw2   = (const float*)d_in[14];
    const float* mb2   = (const float*)d_in[15];
    const float* lw    = (const float*)d_in[16];
    const float* lb    = (const float*)d_in[17];
    float* out = (float*)d_out;
    (void)in_sizes; (void)n_in; (void)out_size; (void)ws_size;

    char* ws = (char*)d_ws;
    size_t off = 0;
    auto carve = [&](size_t bytes) { size_t o = off; off += (bytes + 255) & ~(size_t)255; return o; };
    size_t o_offs  = carve((size_t)Gn * Nn * 4);
    size_t o_deg   = carve((size_t)Gn * Nn * 4);
    size_t o_selfw = carve((size_t)Gn * Nn * 4);
    size_t o_ep    = carve((size_t)Gn * En * 8);
    size_t o_pool  = carve((size_t)Gn * Cc * 4);
    size_t o_H     = carve((size_t)Gn * Nn * Cc * 2);
    size_t o_T     = carve((size_t)Gn * Nn * Cc * 2);

    int*   offs   = (int*)(ws + o_offs);
    int*   degg   = (int*)(ws + o_deg);
    float* selfw  = (float*)(ws + o_selfw);
    int2*  epair  = (int2*)(ws + o_ep);
    float* pooled = (float*)(ws + o_pool);
    unsigned short* H = (unsigned short*)(ws + o_H);
    unsigned short* T = (unsigned short*)(ws + o_T);

    k_prep<<<Gn, 1024, 0, stream>>>(ei, offs, degg, selfw, epair, pooled);
    k_gemm<0><<<256, 256, 0, stream>>>(x, W0, H);
    k_combine<0><<<2048, 256, 0, stream>>>((const unsigned*)H, epair, offs, degg, selfw, b0, (unsigned*)T, nullptr);
    k_gemm<1><<<256, 256, 0, stream>>>(T, W1, H);
    k_combine<1><<<2048, 256, 0, stream>>>((const unsigned*)H, epair, offs, degg, selfw, b1, nullptr, pooled);
    k_head<<<1, 1024, 0, stream>>>(pooled, in_w, in_b, out_w, out_b, mw1, mb1, mw2, mb2, ln2g, ln2b, lw, lb, out);
}

// Round 3
// 233.497 us; speedup vs baseline: 3.5236x; 3.5236x over previous
//
#include <hip/hip_runtime.h>
#include <math.h>

#define Gn 64
#define Nn 1000
#define En 8192
#define Cc 128
#define HIDn 256
#define EPSf 1e-5f

typedef __attribute__((ext_vector_type(8))) short bh8;
typedef __attribute__((ext_vector_type(4))) float fx4;

__device__ __forceinline__ unsigned short f2bf(float f) {
    unsigned u = __float_as_uint(f);
    u += 0x7fffu + ((u >> 16) & 1u);
    return (unsigned short)(u >> 16);
}
__device__ __forceinline__ float bflo(unsigned u) { return __uint_as_float(u << 16); }
__device__ __forceinline__ float bfhi(unsigned u) { return __uint_as_float(u & 0xffff0000u); }

// ---------------- prep: degree count + scan + CSR(src,w) fill, per graph ----------------
__global__ __launch_bounds__(1024) void k_prep(const int* __restrict__ ei, int* __restrict__ offs,
                                               int* __restrict__ degg, float* __restrict__ selfw,
                                               int2* __restrict__ epair, float* __restrict__ pooled)
{
    __shared__ int degs[1024];
    __shared__ int sb[1024];
    __shared__ int cur[1024];
    __shared__ float dinv_s[1024];
    int g = blockIdx.x, t = threadIdx.x;
    const int* srcp = ei + (size_t)g * 2 * En;
    const int* dstp = srcp + En;
    degs[t] = 0;
    __syncthreads();
    for (int e = t; e < En; e += 1024) atomicAdd(&degs[dstp[e]], 1);
    __syncthreads();
    int d = (t < Nn) ? degs[t] : 0;
    sb[t] = d;
    __syncthreads();
    for (int st = 1; st < 1024; st <<= 1) {
        int v2 = (t >= st) ? sb[t - st] : 0;
        __syncthreads();
        sb[t] += v2;
        __syncthreads();
    }
    int ex = sb[t] - d;            // exclusive prefix
    float dv = rsqrtf((float)d + 1.0f);
    cur[t] = ex;
    dinv_s[t] = dv;
    if (t < Nn) {
        offs[g * Nn + t] = ex;
        degg[g * Nn + t] = d;
        selfw[g * Nn + t] = dv * dv;
    }
    __syncthreads();
    for (int e = t; e < En; e += 1024) {
        int dd = dstp[e], ss = srcp[e];
        int p = atomicAdd(&cur[dd], 1);
        float w = dinv_s[ss] * dinv_s[dd];
        epair[(size_t)g * En + p] = make_int2(ss, __float_as_int(w));
    }
    if (t < Cc) pooled[g * Cc + t] = 0.f;  // combine<POOL> accumulates later (same stream)
}

// ---------------- MFMA GEMM: H[g] = X[g] @ W, bf16 out. INBF: input is bf16 (else fp32) ----
template<int INBF>
__global__ __launch_bounds__(256) void k_gemm(const void* __restrict__ Xin, const float* __restrict__ W,
                                              unsigned short* __restrict__ Hout)
{
    __shared__ __align__(16) short Wt[128][136];   // W^T, 272B rows: 16B-aligned, uniform bank spread
    int b = blockIdx.x;
    int xcd = b & 7, j = b >> 3;
    int g = xcd + 8 * (j & 7);     // graph g on XCD g%8
    int rblk = j >> 3;             // 0..3, 256 rows each
    int t = threadIdx.x;
    for (int idx = t; idx < 16384; idx += 256) {
        int kI = idx >> 7, n = idx & 127;
        Wt[n][kI] = (short)f2bf(W[idx]);
    }
    __syncthreads();
    int wave = t >> 6, l = t & 63;
    int lr = l & 15, lg = l >> 4;
    const float* Xf = (const float*)Xin + (size_t)g * Nn * Cc;
    const short* Xh = (const short*)Xin + (size_t)g * Nn * Cc;
    unsigned short* Hg = Hout + (size_t)g * Nn * Cc;

    for (int s = 0; s < 4; ++s) {
        int rbase = rblk * 256 + wave * 64 + s * 16;
        int r = rbase + lr;
        bool ok = r < Nn;
        bh8 af[4];
        if (INBF) {
            #pragma unroll
            for (int ks = 0; ks < 4; ++ks) {
                if (ok) af[ks] = *(const bh8*)(Xh + (size_t)r * Cc + ks * 32 + lg * 8);
                else    af[ks] = bh8{0, 0, 0, 0, 0, 0, 0, 0};
            }
        } else {
            #pragma unroll
            for (int ks = 0; ks < 4; ++ks) {
                if (ok) {
                    const float* xp = Xf + (size_t)r * Cc + ks * 32 + lg * 8;
                    fx4 a0 = *(const fx4*)xp;
                    fx4 a1 = *(const fx4*)(xp + 4);
                    bh8 av;
                    av[0] = (short)f2bf(a0[0]); av[1] = (short)f2bf(a0[1]);
                    av[2] = (short)f2bf(a0[2]); av[3] = (short)f2bf(a0[3]);
                    av[4] = (short)f2bf(a1[0]); av[5] = (short)f2bf(a1[1]);
                    av[6] = (short)f2bf(a1[2]); av[7] = (short)f2bf(a1[3]);
                    af[ks] = av;
                } else af[ks] = bh8{0, 0, 0, 0, 0, 0, 0, 0};
            }
        }
        fx4 acc[8];
        #pragma unroll
        for (int ct = 0; ct < 8; ++ct) acc[ct] = fx4{0.f, 0.f, 0.f, 0.f};
        #pragma unroll
        for (int ks = 0; ks < 4; ++ks) {
            #pragma unroll
            for (int ct = 0; ct < 8; ++ct) {
                bh8 bfr = *(const bh8*)(&Wt[ct * 16 + lr][ks * 32 + lg * 8]);
                acc[ct] = __builtin_amdgcn_mfma_f32_16x16x32_bf16(af[ks], bfr, acc[ct], 0, 0, 0);
            }
        }
        // C/D layout: col = lane&15, row = (lane>>4)*4 + reg
        #pragma unroll
        for (int ct = 0; ct < 8; ++ct) {
            #pragma unroll
            for (int rg = 0; rg < 4; ++rg) {
                int row = rbase + lg * 4 + rg;
                if (row < Nn) Hg[(size_t)row * Cc + ct * 16 + lr] = f2bf(acc[ct][rg]);
            }
        }
    }
}

// ---------------- combine: tanh(b + selfw*H[n] + sum_e w_e*H[src_e]); POOL: accumulate ------
template<int POOL>
__global__ __launch_bounds__(256) void k_combine(const unsigned* __restrict__ Hb, const int2* __restrict__ epair,
                                                 const int* __restrict__ offs, const int* __restrict__ degg,
                                                 const float* __restrict__ selfw, const float* __restrict__ bias,
                                                 unsigned* __restrict__ Tout, float* __restrict__ pooled)
{
    int b = blockIdx.x;
    int xcd = b & 7, j = b >> 3;
    int g = xcd + 8 * (j & 7);     // same XCD as this graph's GEMM blocks
    int blk = j >> 3;              // 0..31
    int wave = threadIdx.x >> 6, lane = threadIdx.x & 63;
    const unsigned* Hg = Hb + (size_t)g * Nn * 64;   // rows of 64 uint = 128 bf16
    const int2* epg = epair + (size_t)g * En;
    float2 bb = *(const float2*)(bias + lane * 2);
    float px = 0.f, py = 0.f;
    for (int n = blk * 4 + wave; n < Nn; n += 128) {
        float sw = selfw[g * Nn + n];
        int st = offs[g * Nn + n];
        int dc = degg[g * Nn + n];
        unsigned hv = Hg[n * 64 + lane];
        float ax = bflo(hv) * sw + bb.x;
        float ay = bfhi(hv) * sw + bb.y;
        float bx = 0.f, by = 0.f;
        int e = 0;
        for (; e + 2 <= dc; e += 2) {
            int2 p0 = epg[st + e];
            int2 p1 = epg[st + e + 1];
            unsigned r0 = Hg[p0.x * 64 + lane];
            unsigned r1 = Hg[p1.x * 64 + lane];
            float w0 = __int_as_float(p0.y), w1 = __int_as_float(p1.y);
            ax = fmaf(bflo(r0), w0, ax); ay = fmaf(bfhi(r0), w0, ay);
            bx = fmaf(bflo(r1), w1, bx); by = fmaf(bfhi(r1), w1, by);
        }
        if (e < dc) {
            int2 p0 = epg[st + e];
            unsigned r0 = Hg[p0.x * 64 + lane];
            float w0 = __int_as_float(p0.y);
            ax = fmaf(bflo(r0), w0, ax); ay = fmaf(bfhi(r0), w0, ay);
        }
        ax += bx; ay += by;
        float tx = tanhf(ax), ty = tanhf(ay);
        if (POOL) { px += tx; py += ty; }
        else Tout[(size_t)(g * Nn + n) * 64 + lane] = ((unsigned)f2bf(ty) << 16) | (unsigned)f2bf(tx);
    }
    if (POOL) {
        atomicAdd(&pooled[g * Cc + lane * 2], px);
        atomicAdd(&pooled[g * Cc + lane * 2 + 1], py);
    }
}

// ---------------- attn: per-head block computes its own q/k/v slices, then attention -------
__global__ __launch_bounds__(1024) void k_attn(const float* __restrict__ pooled, const float* __restrict__ in_w,
                                               const float* __restrict__ in_b, float* __restrict__ ob,
                                               float* __restrict__ repr)
{
    __shared__ float P[64][128];
    __shared__ float q[64][33], kk[64][33], v[64][33];
    __shared__ float S[64][64];
    int h = blockIdx.x, t = threadIdx.x;
    if (h == 0 && t < Cc) repr[t] = 0.f;    // consumed by k_row (later in stream)

    for (int idx = t; idx < 8192; idx += 1024) ((float*)P)[idx] = pooled[idx];
    __syncthreads();

    // q/k/v slices for this head: 64 graphs x 96 cols, dot(128)
    for (int idx = t; idx < 6144; idx += 1024) {
        int i = idx / 96, c = idx - i * 96;
        int sel = c >> 5, cc = c & 31;
        int row = sel * Cc + h * 32 + cc;
        const float* wr = in_w + row * Cc;
        float acc = in_b[row];
        #pragma unroll 4
        for (int k2 = 0; k2 < Cc; ++k2) acc = fmaf(P[i][k2], wr[k2], acc);
        if (sel == 0)      q[i][cc] = acc;
        else if (sel == 1) kk[i][cc] = acc;
        else               v[i][cc] = acc;
    }
    __syncthreads();

    for (int idx = t; idx < 4096; idx += 1024) {
        int i = idx >> 6, jj = idx & 63;
        float acc = 0.f;
        #pragma unroll
        for (int d2 = 0; d2 < 32; ++d2) acc = fmaf(q[i][d2], kk[jj][d2], acc);
        S[i][jj] = acc * 0.17677669529663687f;
    }
    __syncthreads();

    int lane = t & 63, w = t >> 6;
    for (int r = w; r < 64; r += 16) {
        float val = S[r][lane];
        float m = val;
        #pragma unroll
        for (int off = 32; off > 0; off >>= 1) m = fmaxf(m, __shfl_xor(m, off));
        float e2 = expf(val - m);
        float ssum = e2;
        #pragma unroll
        for (int off = 32; off > 0; off >>= 1) ssum += __shfl_xor(ssum, off);
        S[r][lane] = e2 / ssum;
    }
    __syncthreads();

    for (int idx = t; idx < 2048; idx += 1024) {
        int i = idx >> 5, d2 = idx & 31;
        float acc = 0.f;
        #pragma unroll 4
        for (int k2 = 0; k2 < 64; ++k2) acc = fmaf(S[i][k2], v[k2][d2], acc);
        ob[i * Cc + h * 32 + d2] = acc;
    }
}

// ---------------- per-row: out-proj + MLP + LN + relu-accumulate ----------------
__global__ __launch_bounds__(256) void k_row(const float* __restrict__ ob, const float* __restrict__ out_w,
                                             const float* __restrict__ out_b, const float* __restrict__ mw1,
                                             const float* __restrict__ mb1, const float* __restrict__ mw2,
                                             const float* __restrict__ mb2, const float* __restrict__ ln2g,
                                             const float* __restrict__ ln2b, float* __restrict__ repr)
{
    __shared__ float orow[Cc], xatt[Cc], m1[HIDn], ybuf[Cc], red[Cc];
    int i = blockIdx.x, t = threadIdx.x;

    if (t < Cc) orow[t] = ob[i * Cc + t];
    __syncthreads();

    if (t < Cc) {
        float acc = out_b[t];
        #pragma unroll 4
        for (int k = 0; k < Cc; ++k) acc = fmaf(orow[k], out_w[t * Cc + k], acc);
        xatt[t] = acc;
    }
    __syncthreads();

    {   // all 256 threads: m1[t]
        float acc = mb1[t];
        #pragma unroll 4
        for (int k = 0; k < Cc; ++k) acc = fmaf(xatt[k], mw1[k * HIDn + t], acc);
        m1[t] = fmaxf(acc, 0.f);
    }
    __syncthreads();

    if (t < Cc) {
        float acc = mb2[t];
        #pragma unroll 4
        for (int j = 0; j < HIDn; ++j) acc = fmaf(m1[j], mw2[j * Cc + t], acc);
        ybuf[t] = xatt[t] + acc;
    }
    __syncthreads();

    if (t < Cc) red[t] = ybuf[t];
    __syncthreads();
    for (int s2 = 64; s2 > 0; s2 >>= 1) {
        if (t < s2) red[t] += red[t + s2];
        __syncthreads();
    }
    float mu = red[0] * (1.f / Cc);
    __syncthreads();
    if (t < Cc) { float d = ybuf[t] - mu; red[t] = d * d; }
    __syncthreads();
    for (int s2 = 64; s2 > 0; s2 >>= 1) {
        if (t < s2) red[t] += red[t + s2];
        __syncthreads();
    }
    float var = red[0] * (1.f / Cc);
    float rstd = rsqrtf(var + EPSf);
    if (t < Cc) {
        float z = (ybuf[t] - mu) * rstd * ln2g[t] + ln2b[t];
        atomicAdd(&repr[t], fmaxf(z, 0.f));
    }
}

// ---------------- final: logits = repr @ lw + lb ----------------
__global__ __launch_bounds__(128) void k_final(const float* __restrict__ repr, const float* __restrict__ lw,
                                               const float* __restrict__ lb, float* __restrict__ out)
{
    __shared__ float r0[Cc], r1[Cc];
    int t = threadIdx.x;
    float r = repr[t];
    r0[t] = r * lw[t * 2 + 0];
    r1[t] = r * lw[t * 2 + 1];
    __syncthreads();
    for (int s2 = 64; s2 > 0; s2 >>= 1) {
        if (t < s2) { r0[t] += r0[t + s2]; r1[t] += r1[t + s2]; }
        __syncthreads();
    }
    if (t == 0) {
        out[0] = r0[0] + lb[0];
        out[1] = r1[0] + lb[1];
    }
}

extern "C" void kernel_launch(void* const* d_in, const int* in_sizes, int n_in,
                              void* d_out, int out_size, void* d_ws, size_t ws_size,
                              hipStream_t stream)
{
    const float* x     = (const float*)d_in[0];
    const int*   ei    = (const int*)d_in[1];
    const float* W0    = (const float*)d_in[2];
    const float* b0    = (const float*)d_in[3];
    const float* W1    = (const float*)d_in[4];
    const float* b1    = (const float*)d_in[5];
    const float* in_w  = (const float*)d_in[6];
    const float* in_b  = (const float*)d_in[7];
    const float* out_w = (const float*)d_in[8];
    const float* out_b = (const float*)d_in[9];
    const float* ln2g  = (const float*)d_in[10];
    const float* ln2b  = (const float*)d_in[11];
    const float* mw1   = (const float*)d_in[12];
    const float* mb1   = (const float*)d_in[13];
    const float* mw2   = (const float*)d_in[14];
    const float* mb2   = (const float*)d_in[15];
    const float* lw    = (const float*)d_in[16];
    const float* lb    = (const float*)d_in[17];
    float* out = (float*)d_out;
    (void)in_sizes; (void)n_in; (void)out_size; (void)ws_size;

    char* ws = (char*)d_ws;
    size_t off = 0;
    auto carve = [&](size_t bytes) { size_t o = off; off += (bytes + 255) & ~(size_t)255; return o; };
    size_t o_offs  = carve((size_t)Gn * Nn * 4);
    size_t o_deg   = carve((size_t)Gn * Nn * 4);
    size_t o_selfw = carve((size_t)Gn * Nn * 4);
    size_t o_ep    = carve((size_t)Gn * En * 8);
    size_t o_pool  = carve((size_t)Gn * Cc * 4);
    size_t o_ob    = carve((size_t)Gn * Cc * 4);
    size_t o_repr  = carve((size_t)Cc * 4);
    size_t o_H     = carve((size_t)Gn * Nn * Cc * 2);
    size_t o_T     = carve((size_t)Gn * Nn * Cc * 2);

    int*   offs   = (int*)(ws + o_offs);
    int*   degg   = (int*)(ws + o_deg);
    float* selfw  = (float*)(ws + o_selfw);
    int2*  epair  = (int2*)(ws + o_ep);
    float* pooled = (float*)(ws + o_pool);
    float* ob     = (float*)(ws + o_ob);
    float* repr   = (float*)(ws + o_repr);
    unsigned short* H = (unsigned short*)(ws + o_H);
    unsigned short* T = (unsigned short*)(ws + o_T);

    k_prep<<<Gn, 1024, 0, stream>>>(ei, offs, degg, selfw, epair, pooled);
    k_gemm<0><<<256, 256, 0, stream>>>(x, W0, H);
    k_combine<0><<<2048, 256, 0, stream>>>((const unsigned*)H, epair, offs, degg, selfw, b0, (unsigned*)T, nullptr);
    k_gemm<1><<<256, 256, 0, stream>>>(T, W1, H);
    k_combine<1><<<2048, 256, 0, stream>>>((const unsigned*)H, epair, offs, degg, selfw, b1, nullptr, pooled);
    k_attn<<<4, 1024, 0, stream>>>(pooled, in_w, in_b, ob, repr);
    k_row<<<Gn, 256, 0, stream>>>(ob, out_w, out_b, mw1, mb1, mw2, mb2, ln2g, ln2b, repr);
    k_final<<<1, 128, 0, stream>>>(repr, lw, lb, out);
}

// Round 4
// 194.809 us; speedup vs baseline: 4.2234x; 1.1986x over previous
//
#include <hip/hip_runtime.h>
#include <math.h>

#define Gn 64
#define Nn 1000
#define En 8192
#define Cc 128
#define HIDn 256
#define EPSf 1e-5f

typedef __attribute__((ext_vector_type(8))) short bh8;
typedef __attribute__((ext_vector_type(4))) float fx4;

__device__ __forceinline__ unsigned short f2bf(float f) {
    unsigned u = __float_as_uint(f);
    u += 0x7fffu + ((u >> 16) & 1u);
    return (unsigned short)(u >> 16);
}
__device__ __forceinline__ float bflo(unsigned u) { return __uint_as_float(u << 16); }
__device__ __forceinline__ float bfhi(unsigned u) { return __uint_as_float(u & 0xffff0000u); }

// ---------------- prep: degree count + scan + CSR(src,w) fill, per graph ----------------
__global__ __launch_bounds__(1024) void k_prep(const int* __restrict__ ei, int* __restrict__ offs,
                                               int* __restrict__ degg, float* __restrict__ selfw,
                                               int2* __restrict__ epair, float* __restrict__ pooled)
{
    __shared__ int degs[1024];
    __shared__ int sb[1024];
    __shared__ int cur[1024];
    __shared__ float dinv_s[1024];
    int g = blockIdx.x, t = threadIdx.x;
    const int* srcp = ei + (size_t)g * 2 * En;
    const int* dstp = srcp + En;
    degs[t] = 0;
    __syncthreads();
    for (int e = t; e < En; e += 1024) atomicAdd(&degs[dstp[e]], 1);
    __syncthreads();
    int d = (t < Nn) ? degs[t] : 0;
    sb[t] = d;
    __syncthreads();
    for (int st = 1; st < 1024; st <<= 1) {
        int v2 = (t >= st) ? sb[t - st] : 0;
        __syncthreads();
        sb[t] += v2;
        __syncthreads();
    }
    int ex = sb[t] - d;            // exclusive prefix
    float dv = rsqrtf((float)d + 1.0f);
    cur[t] = ex;
    dinv_s[t] = dv;
    if (t < Nn) {
        offs[g * Nn + t] = ex;
        degg[g * Nn + t] = d;
        selfw[g * Nn + t] = dv * dv;
    }
    __syncthreads();
    for (int e = t; e < En; e += 1024) {
        int dd = dstp[e], ss = srcp[e];
        int p = atomicAdd(&cur[dd], 1);
        float w = dinv_s[ss] * dinv_s[dd];
        epair[(size_t)g * En + p] = make_int2(ss, __float_as_int(w));
    }
    if (t < Cc) pooled[g * Cc + t] = 0.f;  // combine<POOL> accumulates later (same stream)
}

// ---------------- MFMA GEMM: H[g] = X[g] @ W, bf16 out. INBF: input is bf16 (else fp32) ----
template<int INBF>
__global__ __launch_bounds__(256) void k_gemm(const void* __restrict__ Xin, const float* __restrict__ W,
                                              unsigned short* __restrict__ Hout)
{
    __shared__ __align__(16) short Wt[128][136];   // W^T, 272B rows: 16B-aligned, uniform bank spread
    int b = blockIdx.x;
    int xcd = b & 7, j = b >> 3;
    int g = xcd + 8 * (j & 7);     // graph g on XCD g%8
    int rblk = j >> 3;             // 0..3, 256 rows each
    int t = threadIdx.x;
    for (int idx = t; idx < 16384; idx += 256) {
        int kI = idx >> 7, n = idx & 127;
        Wt[n][kI] = (short)f2bf(W[idx]);
    }
    __syncthreads();
    int wave = t >> 6, l = t & 63;
    int lr = l & 15, lg = l >> 4;
    const float* Xf = (const float*)Xin + (size_t)g * Nn * Cc;
    const short* Xh = (const short*)Xin + (size_t)g * Nn * Cc;
    unsigned short* Hg = Hout + (size_t)g * Nn * Cc;

    for (int s = 0; s < 4; ++s) {
        int rbase = rblk * 256 + wave * 64 + s * 16;
        int r = rbase + lr;
        bool ok = r < Nn;
        bh8 af[4];
        if (INBF) {
            #pragma unroll
            for (int ks = 0; ks < 4; ++ks) {
                if (ok) af[ks] = *(const bh8*)(Xh + (size_t)r * Cc + ks * 32 + lg * 8);
                else    af[ks] = bh8{0, 0, 0, 0, 0, 0, 0, 0};
            }
        } else {
            #pragma unroll
            for (int ks = 0; ks < 4; ++ks) {
                if (ok) {
                    const float* xp = Xf + (size_t)r * Cc + ks * 32 + lg * 8;
                    fx4 a0 = *(const fx4*)xp;
                    fx4 a1 = *(const fx4*)(xp + 4);
                    bh8 av;
                    av[0] = (short)f2bf(a0[0]); av[1] = (short)f2bf(a0[1]);
                    av[2] = (short)f2bf(a0[2]); av[3] = (short)f2bf(a0[3]);
                    av[4] = (short)f2bf(a1[0]); av[5] = (short)f2bf(a1[1]);
                    av[6] = (short)f2bf(a1[2]); av[7] = (short)f2bf(a1[3]);
                    af[ks] = av;
                } else af[ks] = bh8{0, 0, 0, 0, 0, 0, 0, 0};
            }
        }
        fx4 acc[8];
        #pragma unroll
        for (int ct = 0; ct < 8; ++ct) acc[ct] = fx4{0.f, 0.f, 0.f, 0.f};
        #pragma unroll
        for (int ks = 0; ks < 4; ++ks) {
            #pragma unroll
            for (int ct = 0; ct < 8; ++ct) {
                bh8 bfr = *(const bh8*)(&Wt[ct * 16 + lr][ks * 32 + lg * 8]);
                acc[ct] = __builtin_amdgcn_mfma_f32_16x16x32_bf16(af[ks], bfr, acc[ct], 0, 0, 0);
            }
        }
        // C/D layout: col = lane&15, row = (lane>>4)*4 + reg
        #pragma unroll
        for (int ct = 0; ct < 8; ++ct) {
            #pragma unroll
            for (int rg = 0; rg < 4; ++rg) {
                int row = rbase + lg * 4 + rg;
                if (row < Nn) Hg[(size_t)row * Cc + ct * 16 + lr] = f2bf(acc[ct][rg]);
            }
        }
    }
}

// ---------------- combine: tanh(b + selfw*H[n] + sum_e w_e*H[src_e]); POOL: accumulate ------
template<int POOL>
__global__ __launch_bounds__(256) void k_combine(const unsigned* __restrict__ Hb, const int2* __restrict__ epair,
                                                 const int* __restrict__ offs, const int* __restrict__ degg,
                                                 const float* __restrict__ selfw, const float* __restrict__ bias,
                                                 unsigned* __restrict__ Tout, float* __restrict__ pooled)
{
    int b = blockIdx.x;
    int xcd = b & 7, j = b >> 3;
    int g = xcd + 8 * (j & 7);     // same XCD as this graph's GEMM blocks
    int blk = j >> 3;              // 0..31
    int wave = threadIdx.x >> 6, lane = threadIdx.x & 63;
    const unsigned* Hg = Hb + (size_t)g * Nn * 64;   // rows of 64 uint = 128 bf16
    const int2* epg = epair + (size_t)g * En;
    float2 bb = *(const float2*)(bias + lane * 2);
    float px = 0.f, py = 0.f;
    for (int n = blk * 4 + wave; n < Nn; n += 128) {
        float sw = selfw[g * Nn + n];
        int st = offs[g * Nn + n];
        int dc = degg[g * Nn + n];
        unsigned hv = Hg[n * 64 + lane];
        float ax = bflo(hv) * sw + bb.x;
        float ay = bfhi(hv) * sw + bb.y;
        float bx = 0.f, by = 0.f;
        int e = 0;
        for (; e + 2 <= dc; e += 2) {
            int2 p0 = epg[st + e];
            int2 p1 = epg[st + e + 1];
            unsigned r0 = Hg[p0.x * 64 + lane];
            unsigned r1 = Hg[p1.x * 64 + lane];
            float w0 = __int_as_float(p0.y), w1 = __int_as_float(p1.y);
            ax = fmaf(bflo(r0), w0, ax); ay = fmaf(bfhi(r0), w0, ay);
            bx = fmaf(bflo(r1), w1, bx); by = fmaf(bfhi(r1), w1, by);
        }
        if (e < dc) {
            int2 p0 = epg[st + e];
            unsigned r0 = Hg[p0.x * 64 + lane];
            float w0 = __int_as_float(p0.y);
            ax = fmaf(bflo(r0), w0, ax); ay = fmaf(bfhi(r0), w0, ay);
        }
        ax += bx; ay += by;
        float tx = tanhf(ax), ty = tanhf(ay);
        if (POOL) { px += tx; py += ty; }
        else Tout[(size_t)(g * Nn + n) * 64 + lane] = ((unsigned)f2bf(ty) << 16) | (unsigned)f2bf(tx);
    }
    if (POOL) {
        atomicAdd(&pooled[g * Cc + lane * 2], px);
        atomicAdd(&pooled[g * Cc + lane * 2 + 1], py);
    }
}

// ---------------- qkv: one wave per output column (coalesced rows + shuffle reduce) -------
__global__ __launch_bounds__(1024) void k_qkv(const float* __restrict__ pooled, const float* __restrict__ in_w,
                                              const float* __restrict__ in_b, float* __restrict__ qkvb,
                                              float* __restrict__ repr)
{
    int t = threadIdx.x, lane = t & 63, wv = t >> 6;
    int c = blockIdx.x * 16 + wv;          // 24 blocks * 16 waves = 384 columns
    if (blockIdx.x == 0 && t < Cc) repr[t] = 0.f;   // consumed by k_row (later in stream)
    const float* wr = in_w + c * Cc;
    float w0 = wr[lane], w1 = wr[64 + lane];
    float bias = in_b[c];
    for (int i = 0; i < Gn; ++i) {
        float p = fmaf(pooled[i * Cc + lane], w0, pooled[i * Cc + 64 + lane] * w1);
        #pragma unroll
        for (int off2 = 32; off2 > 0; off2 >>= 1) p += __shfl_xor(p, off2);
        if (lane == 0) qkvb[i * 384 + c] = p + bias;
    }
}

// ---------------- attn: per-head block, pure LDS ----------------
__global__ __launch_bounds__(1024) void k_attn(const float* __restrict__ qkvb, float* __restrict__ ob)
{
    __shared__ float q[64][33], kk[64][33], v[64][33];
    __shared__ float S[64][64];
    int h = blockIdx.x, t = threadIdx.x;

    for (int idx = t; idx < 2048; idx += 1024) {
        int i = idx >> 5, cc = idx & 31;
        q[i][cc]  = qkvb[i * 384 + h * 32 + cc];
        kk[i][cc] = qkvb[i * 384 + 128 + h * 32 + cc];
        v[i][cc]  = qkvb[i * 384 + 256 + h * 32 + cc];
    }
    __syncthreads();

    for (int idx = t; idx < 4096; idx += 1024) {
        int i = idx >> 6, jj = idx & 63;
        float acc = 0.f;
        #pragma unroll
        for (int d2 = 0; d2 < 32; ++d2) acc = fmaf(q[i][d2], kk[jj][d2], acc);
        S[i][jj] = acc * 0.17677669529663687f;
    }
    __syncthreads();

    int lane = t & 63, w = t >> 6;
    for (int r = w; r < 64; r += 16) {
        float val = S[r][lane];
        float m = val;
        #pragma unroll
        for (int off = 32; off > 0; off >>= 1) m = fmaxf(m, __shfl_xor(m, off));
        float e2 = expf(val - m);
        float ssum = e2;
        #pragma unroll
        for (int off = 32; off > 0; off >>= 1) ssum += __shfl_xor(ssum, off);
        S[r][lane] = e2 / ssum;
    }
    __syncthreads();

    for (int idx = t; idx < 2048; idx += 1024) {
        int i = idx >> 5, d2 = idx & 31;
        float acc = 0.f;
        #pragma unroll 4
        for (int k2 = 0; k2 < 64; ++k2) acc = fmaf(S[i][k2], v[k2][d2], acc);
        ob[i * Cc + h * 32 + d2] = acc;
    }
}

// ---------------- per-row: out-proj(wave-reduce) + MLP + LN + relu-accumulate --------------
__global__ __launch_bounds__(256) void k_row(const float* __restrict__ ob, const float* __restrict__ out_w,
                                             const float* __restrict__ out_b, const float* __restrict__ mw1,
                                             const float* __restrict__ mb1, const float* __restrict__ mw2,
                                             const float* __restrict__ mb2, const float* __restrict__ ln2g,
                                             const float* __restrict__ ln2b, float* __restrict__ repr)
{
    __shared__ float orow[Cc], xatt[Cc], m1[HIDn], ybuf[Cc], red[Cc];
    int i = blockIdx.x, t = threadIdx.x;
    int lane = t & 63, wv = t >> 6;

    if (t < Cc) orow[t] = ob[i * Cc + t];
    __syncthreads();

    float o0 = orow[lane], o1 = orow[64 + lane];
    for (int c = wv; c < Cc; c += 4) {
        const float* wr = out_w + c * Cc;
        float p = fmaf(o0, wr[lane], o1 * wr[64 + lane]);
        #pragma unroll
        for (int off2 = 32; off2 > 0; off2 >>= 1) p += __shfl_xor(p, off2);
        if (lane == 0) xatt[c] = p + out_b[c];
    }
    __syncthreads();

    {   // all 256 threads: m1[t] (mw1 reads coalesced along t)
        float acc = mb1[t];
        #pragma unroll 4
        for (int k = 0; k < Cc; ++k) acc = fmaf(xatt[k], mw1[k * HIDn + t], acc);
        m1[t] = fmaxf(acc, 0.f);
    }
    __syncthreads();

    if (t < Cc) {
        float acc = mb2[t];
        #pragma unroll 4
        for (int j = 0; j < HIDn; ++j) acc = fmaf(m1[j], mw2[j * Cc + t], acc);
        ybuf[t] = xatt[t] + acc;
    }
    __syncthreads();

    if (t < Cc) red[t] = ybuf[t];
    __syncthreads();
    for (int s2 = 64; s2 > 0; s2 >>= 1) {
        if (t < s2) red[t] += red[t + s2];
        __syncthreads();
    }
    float mu = red[0] * (1.f / Cc);
    __syncthreads();
    if (t < Cc) { float d = ybuf[t] - mu; red[t] = d * d; }
    __syncthreads();
    for (int s2 = 64; s2 > 0; s2 >>= 1) {
        if (t < s2) red[t] += red[t + s2];
        __syncthreads();
    }
    float var = red[0] * (1.f / Cc);
    float rstd = rsqrtf(var + EPSf);
    if (t < Cc) {
        float z = (ybuf[t] - mu) * rstd * ln2g[t] + ln2b[t];
        atomicAdd(&repr[t], fmaxf(z, 0.f));
    }
}

// ---------------- final: logits = repr @ lw + lb ----------------
__global__ __launch_bounds__(128) void k_final(const float* __restrict__ repr, const float* __restrict__ lw,
                                               const float* __restrict__ lb, float* __restrict__ out)
{
    __shared__ float r0[Cc], r1[Cc];
    int t = threadIdx.x;
    float r = repr[t];
    r0[t] = r * lw[t * 2 + 0];
    r1[t] = r * lw[t * 2 + 1];
    __syncthreads();
    for (int s2 = 64; s2 > 0; s2 >>= 1) {
        if (t < s2) { r0[t] += r0[t + s2]; r1[t] += r1[t + s2]; }
        __syncthreads();
    }
    if (t == 0) {
        out[0] = r0[0] + lb[0];
        out[1] = r1[0] + lb[1];
    }
}

extern "C" void kernel_launch(void* const* d_in, const int* in_sizes, int n_in,
                              void* d_out, int out_size, void* d_ws, size_t ws_size,
                              hipStream_t stream)
{
    const float* x     = (const float*)d_in[0];
    const int*   ei    = (const int*)d_in[1];
    const float* W0    = (const float*)d_in[2];
    const float* b0    = (const float*)d_in[3];
    const float* W1    = (const float*)d_in[4];
    const float* b1    = (const float*)d_in[5];
    const float* in_w  = (const float*)d_in[6];
    const float* in_b  = (const float*)d_in[7];
    const float* out_w = (const float*)d_in[8];
    const float* out_b = (const float*)d_in[9];
    const float* ln2g  = (const float*)d_in[10];
    const float* ln2b  = (const float*)d_in[11];
    const float* mw1   = (const float*)d_in[12];
    const float* mb1   = (const float*)d_in[13];
    const float* mw2   = (const float*)d_in[14];
    const float* mb2   = (const float*)d_in[15];
    const float* lw    = (const float*)d_in[16];
    const float* lb    = (const float*)d_in[17];
    float* out = (float*)d_out;
    (void)in_sizes; (void)n_in; (void)out_size; (void)ws_size;

    char* ws = (char*)d_ws;
    size_t off = 0;
    auto carve = [&](size_t bytes) { size_t o = off; off += (bytes + 255) & ~(size_t)255; return o; };
    size_t o_offs  = carve((size_t)Gn * Nn * 4);
    size_t o_deg   = carve((size_t)Gn * Nn * 4);
    size_t o_selfw = carve((size_t)Gn * Nn * 4);
    size_t o_ep    = carve((size_t)Gn * En * 8);
    size_t o_pool  = carve((size_t)Gn * Cc * 4);
    size_t o_qkv   = carve((size_t)Gn * 384 * 4);
    size_t o_ob    = carve((size_t)Gn * Cc * 4);
    size_t o_repr  = carve((size_t)Cc * 4);
    size_t o_H     = carve((size_t)Gn * Nn * Cc * 2);
    size_t o_T     = carve((size_t)Gn * Nn * Cc * 2);

    int*   offs   = (int*)(ws + o_offs);
    int*   degg   = (int*)(ws + o_deg);
    float* selfw  = (float*)(ws + o_selfw);
    int2*  epair  = (int2*)(ws + o_ep);
    float* pooled = (float*)(ws + o_pool);
    float* qkvb   = (float*)(ws + o_qkv);
    float* ob     = (float*)(ws + o_ob);
    float* repr   = (float*)(ws + o_repr);
    unsigned short* H = (unsigned short*)(ws + o_H);
    unsigned short* T = (unsigned short*)(ws + o_T);

    k_prep<<<Gn, 1024, 0, stream>>>(ei, offs, degg, selfw, epair, pooled);
    k_gemm<0><<<256, 256, 0, stream>>>(x, W0, H);
    k_combine<0><<<2048, 256, 0, stream>>>((const unsigned*)H, epair, offs, degg, selfw, b0, (unsigned*)T, nullptr);
    k_gemm<1><<<256, 256, 0, stream>>>(T, W1, H);
    k_combine<1><<<2048, 256, 0, stream>>>((const unsigned*)H, epair, offs, degg, selfw, b1, nullptr, pooled);
    k_qkv<<<24, 1024, 0, stream>>>(pooled, in_w, in_b, qkvb, repr);
    k_attn<<<4, 1024, 0, stream>>>(qkvb, ob);
    k_row<<<Gn, 256, 0, stream>>>(ob, out_w, out_b, mw1, mb1, mw2, mb2, ln2g, ln2b, repr);
    k_final<<<1, 128, 0, stream>>>(repr, lw, lb, out);
}

// Round 5
// 175.088 us; speedup vs baseline: 4.6991x; 1.1126x over previous
//
#include <hip/hip_runtime.h>
#include <math.h>

#define Gn 64
#define Nn 1000
#define En 8192
#define Cc 128
#define HIDn 256
#define EPSf 1e-5f

typedef __attribute__((ext_vector_type(8))) short bh8;
typedef __attribute__((ext_vector_type(4))) float fx4;

__device__ __forceinline__ unsigned short f2bf(float f) {
    unsigned u = __float_as_uint(f);
    u += 0x7fffu + ((u >> 16) & 1u);
    return (unsigned short)(u >> 16);
}
__device__ __forceinline__ float bflo(unsigned u) { return __uint_as_float(u << 16); }
__device__ __forceinline__ float bfhi(unsigned u) { return __uint_as_float(u & 0xffff0000u); }

// ---------------- prep: degree count + scan + CSR(src,w) fill, per graph ----------------
__global__ __launch_bounds__(1024) void k_prep(const int* __restrict__ ei, int* __restrict__ offs,
                                               int* __restrict__ degg, float* __restrict__ selfw,
                                               int2* __restrict__ epair, float* __restrict__ pooled)
{
    __shared__ int degs[1024];
    __shared__ int sb[1024];
    __shared__ int cur[1024];
    __shared__ float dinv_s[1024];
    int g = blockIdx.x, t = threadIdx.x;
    const int* srcp = ei + (size_t)g * 2 * En;
    const int* dstp = srcp + En;
    degs[t] = 0;
    __syncthreads();
    for (int e = t; e < En; e += 1024) atomicAdd(&degs[dstp[e]], 1);
    __syncthreads();
    int d = (t < Nn) ? degs[t] : 0;
    sb[t] = d;
    __syncthreads();
    for (int st = 1; st < 1024; st <<= 1) {
        int v2 = (t >= st) ? sb[t - st] : 0;
        __syncthreads();
        sb[t] += v2;
        __syncthreads();
    }
    int ex = sb[t] - d;            // exclusive prefix
    float dv = rsqrtf((float)d + 1.0f);
    cur[t] = ex;
    dinv_s[t] = dv;
    if (t < Nn) {
        offs[g * Nn + t] = ex;
        degg[g * Nn + t] = d;
        selfw[g * Nn + t] = dv * dv;
    }
    __syncthreads();
    for (int e = t; e < En; e += 1024) {
        int dd = dstp[e], ss = srcp[e];
        int p = atomicAdd(&cur[dd], 1);
        float w = dinv_s[ss] * dinv_s[dd];
        epair[(size_t)g * En + p] = make_int2(ss, __float_as_int(w));
    }
    if (t < Cc) pooled[g * Cc + t] = 0.f;  // combine<POOL> accumulates later (same stream)
}

// ---------------- MFMA GEMM: H[g] = X[g] @ W, bf16 out. INBF: input is bf16 (else fp32) ----
template<int INBF>
__global__ __launch_bounds__(256) void k_gemm(const void* __restrict__ Xin, const float* __restrict__ W,
                                              unsigned short* __restrict__ Hout)
{
    __shared__ __align__(16) short Wt[128][136];   // W^T, 272B rows: 16B-aligned, uniform bank spread
    int b = blockIdx.x;
    int xcd = b & 7, j = b >> 3;
    int g = xcd + 8 * (j & 7);     // graph g on XCD g%8
    int rblk = j >> 3;             // 0..3, 256 rows each
    int t = threadIdx.x;
    for (int idx = t; idx < 16384; idx += 256) {
        int kI = idx >> 7, n = idx & 127;
        Wt[n][kI] = (short)f2bf(W[idx]);
    }
    __syncthreads();
    int wave = t >> 6, l = t & 63;
    int lr = l & 15, lg = l >> 4;
    const float* Xf = (const float*)Xin + (size_t)g * Nn * Cc;
    const short* Xh = (const short*)Xin + (size_t)g * Nn * Cc;
    unsigned short* Hg = Hout + (size_t)g * Nn * Cc;

    for (int s = 0; s < 4; ++s) {
        int rbase = rblk * 256 + wave * 64 + s * 16;
        int r = rbase + lr;
        bool ok = r < Nn;
        bh8 af[4];
        if (INBF) {
            #pragma unroll
            for (int ks = 0; ks < 4; ++ks) {
                if (ok) af[ks] = *(const bh8*)(Xh + (size_t)r * Cc + ks * 32 + lg * 8);
                else    af[ks] = bh8{0, 0, 0, 0, 0, 0, 0, 0};
            }
        } else {
            #pragma unroll
            for (int ks = 0; ks < 4; ++ks) {
                if (ok) {
                    const float* xp = Xf + (size_t)r * Cc + ks * 32 + lg * 8;
                    fx4 a0 = *(const fx4*)xp;
                    fx4 a1 = *(const fx4*)(xp + 4);
                    bh8 av;
                    av[0] = (short)f2bf(a0[0]); av[1] = (short)f2bf(a0[1]);
                    av[2] = (short)f2bf(a0[2]); av[3] = (short)f2bf(a0[3]);
                    av[4] = (short)f2bf(a1[0]); av[5] = (short)f2bf(a1[1]);
                    av[6] = (short)f2bf(a1[2]); av[7] = (short)f2bf(a1[3]);
                    af[ks] = av;
                } else af[ks] = bh8{0, 0, 0, 0, 0, 0, 0, 0};
            }
        }
        fx4 acc[8];
        #pragma unroll
        for (int ct = 0; ct < 8; ++ct) acc[ct] = fx4{0.f, 0.f, 0.f, 0.f};
        #pragma unroll
        for (int ks = 0; ks < 4; ++ks) {
            #pragma unroll
            for (int ct = 0; ct < 8; ++ct) {
                bh8 bfr = *(const bh8*)(&Wt[ct * 16 + lr][ks * 32 + lg * 8]);
                acc[ct] = __builtin_amdgcn_mfma_f32_16x16x32_bf16(af[ks], bfr, acc[ct], 0, 0, 0);
            }
        }
        // C/D layout: col = lane&15, row = (lane>>4)*4 + reg
        #pragma unroll
        for (int ct = 0; ct < 8; ++ct) {
            #pragma unroll
            for (int rg = 0; rg < 4; ++rg) {
                int row = rbase + lg * 4 + rg;
                if (row < Nn) Hg[(size_t)row * Cc + ct * 16 + lr] = f2bf(acc[ct][rg]);
            }
        }
    }
}

// ---------------- combine: tanh(b + selfw*H[n] + sum_e w_e*H[src_e]); POOL: accumulate ------
template<int POOL>
__global__ __launch_bounds__(256) void k_combine(const unsigned* __restrict__ Hb, const int2* __restrict__ epair,
                                                 const int* __restrict__ offs, const int* __restrict__ degg,
                                                 const float* __restrict__ selfw, const float* __restrict__ bias,
                                                 unsigned* __restrict__ Tout, float* __restrict__ pooled)
{
    int b = blockIdx.x;
    int xcd = b & 7, j = b >> 3;
    int g = xcd + 8 * (j & 7);     // same XCD as this graph's GEMM blocks
    int blk = j >> 3;              // 0..31
    int wave = threadIdx.x >> 6, lane = threadIdx.x & 63;
    const unsigned* Hg = Hb + (size_t)g * Nn * 64;   // rows of 64 uint = 128 bf16
    const int2* epg = epair + (size_t)g * En;
    float2 bb = *(const float2*)(bias + lane * 2);
    float px = 0.f, py = 0.f;
    for (int n = blk * 4 + wave; n < Nn; n += 128) {
        float sw = selfw[g * Nn + n];
        int st = offs[g * Nn + n];
        int dc = degg[g * Nn + n];
        unsigned hv = Hg[n * 64 + lane];
        float ax = bflo(hv) * sw + bb.x;
        float ay = bfhi(hv) * sw + bb.y;
        float bx = 0.f, by = 0.f;
        int e = 0;
        for (; e + 2 <= dc; e += 2) {
            int2 p0 = epg[st + e];
            int2 p1 = epg[st + e + 1];
            unsigned r0 = Hg[p0.x * 64 + lane];
            unsigned r1 = Hg[p1.x * 64 + lane];
            float w0 = __int_as_float(p0.y), w1 = __int_as_float(p1.y);
            ax = fmaf(bflo(r0), w0, ax); ay = fmaf(bfhi(r0), w0, ay);
            bx = fmaf(bflo(r1), w1, bx); by = fmaf(bfhi(r1), w1, by);
        }
        if (e < dc) {
            int2 p0 = epg[st + e];
            unsigned r0 = Hg[p0.x * 64 + lane];
            float w0 = __int_as_float(p0.y);
            ax = fmaf(bflo(r0), w0, ax); ay = fmaf(bfhi(r0), w0, ay);
        }
        ax += bx; ay += by;
        float tx = tanhf(ax), ty = tanhf(ay);
        if (POOL) { px += tx; py += ty; }
        else Tout[(size_t)(g * Nn + n) * 64 + lane] = ((unsigned)f2bf(ty) << 16) | (unsigned)f2bf(tx);
    }
    if (POOL) {
        atomicAdd(&pooled[g * Cc + lane * 2], px);
        atomicAdd(&pooled[g * Cc + lane * 2 + 1], py);
    }
}

// ---------------- qkv: one wave per output column (coalesced rows + shuffle reduce) -------
__global__ __launch_bounds__(1024) void k_qkv(const float* __restrict__ pooled, const float* __restrict__ in_w,
                                              const float* __restrict__ in_b, float* __restrict__ qkvb,
                                              float* __restrict__ repr)
{
    int t = threadIdx.x, lane = t & 63, wv = t >> 6;
    int c = blockIdx.x * 16 + wv;          // 24 blocks * 16 waves = 384 columns
    if (blockIdx.x == 0 && t < Cc) repr[t] = 0.f;   // consumed by k_tail (later in stream)
    const float* wr = in_w + c * Cc;
    float w0 = wr[lane], w1 = wr[64 + lane];
    float bias = in_b[c];
    for (int i = 0; i < Gn; ++i) {
        float p = fmaf(pooled[i * Cc + lane], w0, pooled[i * Cc + 64 + lane] * w1);
        #pragma unroll
        for (int off2 = 32; off2 > 0; off2 >>= 1) p += __shfl_xor(p, off2);
        if (lane == 0) qkvb[i * 384 + c] = p + bias;
    }
}

// ---------------- attn: per-head block, pure LDS ----------------
__global__ __launch_bounds__(1024) void k_attn(const float* __restrict__ qkvb, float* __restrict__ ob)
{
    __shared__ float q[64][33], kk[64][33], v[64][33];
    __shared__ float S[64][64];
    int h = blockIdx.x, t = threadIdx.x;

    for (int idx = t; idx < 2048; idx += 1024) {
        int i = idx >> 5, cc = idx & 31;
        q[i][cc]  = qkvb[i * 384 + h * 32 + cc];
        kk[i][cc] = qkvb[i * 384 + 128 + h * 32 + cc];
        v[i][cc]  = qkvb[i * 384 + 256 + h * 32 + cc];
    }
    __syncthreads();

    for (int idx = t; idx < 4096; idx += 1024) {
        int i = idx >> 6, jj = idx & 63;
        float acc = 0.f;
        #pragma unroll
        for (int d2 = 0; d2 < 32; ++d2) acc = fmaf(q[i][d2], kk[jj][d2], acc);
        S[i][jj] = acc * 0.17677669529663687f;
    }
    __syncthreads();

    int lane = t & 63, w = t >> 6;
    for (int r = w; r < 64; r += 16) {
        float val = S[r][lane];
        float m = val;
        #pragma unroll
        for (int off = 32; off > 0; off >>= 1) m = fmaxf(m, __shfl_xor(m, off));
        float e2 = expf(val - m);
        float ssum = e2;
        #pragma unroll
        for (int off = 32; off > 0; off >>= 1) ssum += __shfl_xor(ssum, off);
        S[r][lane] = e2 / ssum;
    }
    __syncthreads();

    for (int idx = t; idx < 2048; idx += 1024) {
        int i = idx >> 5, d2 = idx & 31;
        float acc = 0.f;
        #pragma unroll 4
        for (int k2 = 0; k2 < 64; ++k2) acc = fmaf(S[i][k2], v[k2][d2], acc);
        ob[i * Cc + h * 32 + d2] = acc;
    }
}

// ---------------- tail: 4 graphs/block: out-proj + MLP + LN + relu-accumulate -------------
__global__ __launch_bounds__(1024) void k_tail(const float* __restrict__ ob, const float* __restrict__ out_w,
                                               const float* __restrict__ out_b, const float* __restrict__ mw1,
                                               const float* __restrict__ mb1, const float* __restrict__ mw2,
                                               const float* __restrict__ mb2, const float* __restrict__ ln2g,
                                               const float* __restrict__ ln2b, float* __restrict__ repr)
{
    __shared__ float sob[4][128];
    __shared__ float sxatt[4][128];
    __shared__ float sm1[4][256];
    __shared__ float spart[4][128];
    __shared__ float pr[128];
    int g0 = blockIdx.x * 4;                 // 16 blocks x 4 graphs
    int t = threadIdx.x, lane = t & 63, wv = t >> 6;

    if (t < 512) sob[t >> 7][t & 127] = ob[(size_t)(g0 + (t >> 7)) * Cc + (t & 127)];
    if (t < 128) pr[t] = 0.f;
    __syncthreads();

    // out-proj: wave per column, weight row register-resident, reused across 4 graphs
    for (int c = wv; c < Cc; c += 16) {
        float w0 = out_w[c * Cc + lane];
        float w1 = out_w[c * Cc + 64 + lane];
        float bc = out_b[c];
        #pragma unroll
        for (int g = 0; g < 4; ++g) {
            float p = fmaf(sob[g][lane], w0, sob[g][64 + lane] * w1);
            #pragma unroll
            for (int off = 32; off > 0; off >>= 1) p += __shfl_xor(p, off);
            if (lane == 0) sxatt[g][c] = p + bc;
        }
    }
    __syncthreads();

    // mlp1: 1024 threads = 256 cols x 4 graphs; mw1 coalesced along j
    {
        int j = t & 255, gi = t >> 8;
        float acc = mb1[j];
        #pragma unroll 8
        for (int k = 0; k < Cc; ++k) acc = fmaf(sxatt[gi][k], mw1[k * HIDn + j], acc);
        sm1[gi][j] = fmaxf(acc, 0.f);
    }
    __syncthreads();

    // mlp2 split-K: 1024 threads = 128 cols x 4 graphs x 2 K-halves; mw2 coalesced along c
    {
        int c = t & 127, gi = (t >> 7) & 3, half = t >> 9;
        int k0 = half * 128;
        float acc = 0.f;
        #pragma unroll 8
        for (int k = 0; k < 128; ++k) acc = fmaf(sm1[gi][k0 + k], mw2[(k0 + k) * Cc + c], acc);
        if (half) spart[gi][c] = acc;
        __syncthreads();
        if (!half) sxatt[gi][c] = sxatt[gi][c] + acc + spart[gi][c] + mb2[c];   // y (residual)
    }
    __syncthreads();

    // LN + relu + per-block accumulate (waves 0..3 = graphs)
    if (t < 256) {
        int g = wv;
        float v0 = sxatt[g][lane], v1 = sxatt[g][64 + lane];
        float s = v0 + v1;
        #pragma unroll
        for (int off = 32; off > 0; off >>= 1) s += __shfl_xor(s, off);
        float mu = s * (1.f / 128.f);
        float d0 = v0 - mu, d1 = v1 - mu;
        float vv = d0 * d0 + d1 * d1;
        #pragma unroll
        for (int off = 32; off > 0; off >>= 1) vv += __shfl_xor(vv, off);
        float rstd = rsqrtf(vv * (1.f / 128.f) + EPSf);
        float z0 = fmaxf(d0 * rstd * ln2g[lane] + ln2b[lane], 0.f);
        float z1 = fmaxf(d1 * rstd * ln2g[64 + lane] + ln2b[64 + lane], 0.f);
        atomicAdd(&pr[lane], z0);
        atomicAdd(&pr[64 + lane], z1);
    }
    __syncthreads();
    if (t < 128) atomicAdd(&repr[t], pr[t]);
}

// ---------------- final: logits = repr @ lw + lb ----------------
__global__ __launch_bounds__(128) void k_final(const float* __restrict__ repr, const float* __restrict__ lw,
                                               const float* __restrict__ lb, float* __restrict__ out)
{
    __shared__ float r0[Cc], r1[Cc];
    int t = threadIdx.x;
    float r = repr[t];
    r0[t] = r * lw[t * 2 + 0];
    r1[t] = r * lw[t * 2 + 1];
    __syncthreads();
    for (int s2 = 64; s2 > 0; s2 >>= 1) {
        if (t < s2) { r0[t] += r0[t + s2]; r1[t] += r1[t + s2]; }
        __syncthreads();
    }
    if (t == 0) {
        out[0] = r0[0] + lb[0];
        out[1] = r1[0] + lb[1];
    }
}

extern "C" void kernel_launch(void* const* d_in, const int* in_sizes, int n_in,
                              void* d_out, int out_size, void* d_ws, size_t ws_size,
                              hipStream_t stream)
{
    const float* x     = (const float*)d_in[0];
    const int*   ei    = (const int*)d_in[1];
    const float* W0    = (const float*)d_in[2];
    const float* b0    = (const float*)d_in[3];
    const float* W1    = (const float*)d_in[4];
    const float* b1    = (const float*)d_in[5];
    const float* in_w  = (const float*)d_in[6];
    const float* in_b  = (const float*)d_in[7];
    const float* out_w = (const float*)d_in[8];
    const float* out_b = (const float*)d_in[9];
    const float* ln2g  = (const float*)d_in[10];
    const float* ln2b  = (const float*)d_in[11];
    const float* mw1   = (const float*)d_in[12];
    const float* mb1   = (const float*)d_in[13];
    const float* mw2   = (const float*)d_in[14];
    const float* mb2   = (const float*)d_in[15];
    const float* lw    = (const float*)d_in[16];
    const float* lb    = (const float*)d_in[17];
    float* out = (float*)d_out;
    (void)in_sizes; (void)n_in; (void)out_size; (void)ws_size;

    char* ws = (char*)d_ws;
    size_t off = 0;
    auto carve = [&](size_t bytes) { size_t o = off; off += (bytes + 255) & ~(size_t)255; return o; };
    size_t o_offs  = carve((size_t)Gn * Nn * 4);
    size_t o_deg   = carve((size_t)Gn * Nn * 4);
    size_t o_selfw = carve((size_t)Gn * Nn * 4);
    size_t o_ep    = carve((size_t)Gn * En * 8);
    size_t o_pool  = carve((size_t)Gn * Cc * 4);
    size_t o_qkv   = carve((size_t)Gn * 384 * 4);
    size_t o_ob    = carve((size_t)Gn * Cc * 4);
    size_t o_repr  = carve((size_t)Cc * 4);
    size_t o_H     = carve((size_t)Gn * Nn * Cc * 2);
    size_t o_T     = carve((size_t)Gn * Nn * Cc * 2);

    int*   offs   = (int*)(ws + o_offs);
    int*   degg   = (int*)(ws + o_deg);
    float* selfw  = (float*)(ws + o_selfw);
    int2*  epair  = (int2*)(ws + o_ep);
    float* pooled = (float*)(ws + o_pool);
    float* qkvb   = (float*)(ws + o_qkv);
    float* ob     = (float*)(ws + o_ob);
    float* repr   = (float*)(ws + o_repr);
    unsigned short* H = (unsigned short*)(ws + o_H);
    unsigned short* T = (unsigned short*)(ws + o_T);

    k_prep<<<Gn, 1024, 0, stream>>>(ei, offs, degg, selfw, epair, pooled);
    k_gemm<0><<<256, 256, 0, stream>>>(x, W0, H);
    k_combine<0><<<2048, 256, 0, stream>>>((const unsigned*)H, epair, offs, degg, selfw, b0, (unsigned*)T, nullptr);
    k_gemm<1><<<256, 256, 0, stream>>>(T, W1, H);
    k_combine<1><<<2048, 256, 0, stream>>>((const unsigned*)H, epair, offs, degg, selfw, b1, nullptr, pooled);
    k_qkv<<<24, 1024, 0, stream>>>(pooled, in_w, in_b, qkvb, repr);
    k_attn<<<4, 1024, 0, stream>>>(qkvb, ob);
    k_tail<<<16, 1024, 0, stream>>>(ob, out_w, out_b, mw1, mb1, mw2, mb2, ln2g, ln2b, repr);
    k_final<<<1, 128, 0, stream>>>(repr, lw, lb, out);
}